// Round 5
// baseline (725.438 us; speedup 1.0000x reference)
//
#include <hip/hip_runtime.h>

#define BK 32
#define GEMM_THREADS 512
#define LROW 36   // ushorts per LDS row: 32 data + 4 pad (72 B stride)

typedef float f32x4 __attribute__((ext_vector_type(4)));
typedef short s16x8 __attribute__((ext_vector_type(8)));

__device__ __forceinline__ unsigned short f2bf(float f) {
  union { float f; unsigned u; } v; v.f = f;
  return (unsigned short)((v.u + 0x7FFFu + ((v.u >> 16) & 1u)) >> 16);  // RTNE
}

__global__ void __launch_bounds__(64) zero_kernel(float* out) {
  if (threadIdx.x == 0) out[0] = 0.f;
}

// Non-draining barrier: lgkmcnt(0) (my ds ops done) + s_barrier + sched pin.
// Does NOT wait vmcnt -> prefetched global loads stay in flight across it.
__device__ __forceinline__ void barrier_nodrain() {
  asm volatile("s_waitcnt lgkmcnt(0)" ::: "memory");
  __builtin_amdgcn_s_barrier();
  __builtin_amdgcn_sched_barrier(0);
}

// Split-K GEMM: block b owns K-chunk [b*KC,(b+1)*KC), computes full 256x256
// partial into ws + b*65536 (fp16 storage).
// Grid = 512 (KC=512): 2 blocks/CU -> 4 waves/SIMD, uncorrelated barriers.
// LDS 72 KiB/block so two blocks fit the 160 KiB pool.
__global__ void __launch_bounds__(GEMM_THREADS, 4)
gemm_kernel(const float* __restrict__ V1, const float* __restrict__ V2,
            _Float16* __restrict__ ws, int D, int KC) {
  __shared__ __align__(16) unsigned short lds[2 * 2 * 256 * LROW];  // 72 KiB

  const int tid  = threadIdx.x;
  const int lane = tid & 63;
  const int wid  = tid >> 6;
  const int wm   = wid >> 2;   // 0..1
  const int wn   = wid & 3;    // 0..3
  const int lr   = lane & 15;
  const int lg   = lane >> 4;

  const int r0 = tid >> 3;     // staging base row 0..63
  const int c8 = tid & 7;      // 16B segment within row
  const int nsteps = KC / BK;

  f32x4 acc[8][4];
#pragma unroll
  for (int a = 0; a < 8; ++a)
#pragma unroll
    for (int b = 0; b < 4; ++b) acc[a][b] = f32x4{0.f, 0.f, 0.f, 0.f};

  const float* pA[4];
  const float* pB[4];
  {
    const size_t kbase = (size_t)blockIdx.x * (size_t)KC + (size_t)c8 * 4;
#pragma unroll
    for (int q = 0; q < 4; ++q) {
      size_t r = (size_t)(r0 + 64 * q);
      pA[q] = V1 + r * (size_t)D + kbase;
      pB[q] = V2 + r * (size_t)D + kbase;
    }
  }

  float4 sa[4], sb[4];

  auto issue = [&](int t) {
#pragma unroll
    for (int q = 0; q < 4; ++q) {
      sa[q] = *(const float4*)(pA[q] + (size_t)t * BK);
      sb[q] = *(const float4*)(pB[q] + (size_t)t * BK);
    }
  };
  auto lwrite = [&](int buf) {
#pragma unroll
    for (int q = 0; q < 4; ++q) {
      int r  = r0 + 64 * q;
      int ua = ((buf * 2 + 0) * 256 + r) * LROW + c8 * 4;
      int ub = ((buf * 2 + 1) * 256 + r) * LROW + c8 * 4;
      ushort4 wa, wb;
      wa.x = f2bf(sa[q].x); wa.y = f2bf(sa[q].y); wa.z = f2bf(sa[q].z); wa.w = f2bf(sa[q].w);
      wb.x = f2bf(sb[q].x); wb.y = f2bf(sb[q].y); wb.z = f2bf(sb[q].z); wb.w = f2bf(sb[q].w);
      *(ushort4*)&lds[ua] = wa;
      *(ushort4*)&lds[ub] = wb;
    }
  };

  issue(0);
  lwrite(0);
  if (nsteps > 1) issue(1);
  barrier_nodrain();

  for (int t = 0; t < nsteps; ++t) {
    const int buf = t & 1;

    s16x8 af[8], bfr[4];
#pragma unroll
    for (int mf = 0; mf < 8; ++mf) {
      int r = wm * 128 + mf * 16 + lr;
      af[mf] = *(const s16x8*)&lds[((buf * 2 + 0) * 256 + r) * LROW + lg * 8];
    }
#pragma unroll
    for (int nf = 0; nf < 4; ++nf) {
      int r = wn * 64 + nf * 16 + lr;
      bfr[nf] = *(const s16x8*)&lds[((buf * 2 + 1) * 256 + r) * LROW + lg * 8];
    }
#pragma unroll
    for (int mf = 0; mf < 8; ++mf)
#pragma unroll
      for (int nf = 0; nf < 4; ++nf)
        acc[mf][nf] = __builtin_amdgcn_mfma_f32_16x16x32_bf16(af[mf], bfr[nf], acc[mf][nf], 0, 0, 0);

    if (t + 1 < nsteps) {
      lwrite(buf ^ 1);               // waits (reg deps) only loads(t+1)
      if (t + 2 < nsteps) issue(t + 2);  // stays in flight across the barrier
    }
    barrier_nodrain();
  }

  // C/D layout: col = lane&15, row = (lane>>4)*4 + reg. fp16 partial storage
  // (partial ~ N(0, KC): |max| ~ 6*sqrt(512) ~ 140 << 65504; error ~1e-6 on zmean).
  _Float16* Cp = ws + (size_t)blockIdx.x * (256 * 256);
#pragma unroll
  for (int mf = 0; mf < 8; ++mf) {
    int i0 = wm * 128 + mf * 16 + lg * 4;
#pragma unroll
    for (int nf = 0; nf < 4; ++nf) {
      int j = wn * 64 + nf * 16 + lr;
#pragma unroll
      for (int v = 0; v < 4; ++v)
        Cp[(size_t)(i0 + v) * 256 + j] = (_Float16)acc[mf][nf][v];
    }
  }
}

// Sum P fp16 partials, z = dot/D, BCE vs identity labels:
//   diag: softplus(z) - z ; off-diag: softplus(z)
__global__ void __launch_bounds__(256)
loss_kernel(const _Float16* __restrict__ ws, float* __restrict__ out, int P, float invD) {
  const int i = blockIdx.x, j = threadIdx.x;
  const _Float16* base = ws + i * 256 + j;
  float s = 0.f;
#pragma unroll 8
  for (int p = 0; p < P; ++p) s += (float)base[(size_t)p * 65536];
  float z = s * invD;
  float term = log1pf(expf(z)) - (i == j ? z : 0.f);

  __shared__ float red[256];
  red[j] = term;
  __syncthreads();
  for (int st = 128; st > 0; st >>= 1) {
    if (j < st) red[j] += red[j + st];
    __syncthreads();
  }
  if (j == 0) atomicAdd(out, red[0] * (1.f / 65536.f));
}

extern "C" void kernel_launch(void* const* d_in, const int* in_sizes, int n_in,
                              void* d_out, int out_size, void* d_ws, size_t ws_size,
                              hipStream_t stream) {
  const float* V1 = (const float*)d_in[0];
  const float* V2 = (const float*)d_in[1];
  float* out = (float*)d_out;
  _Float16* ws = (_Float16*)d_ws;

  const int N = 256;
  const int D = in_sizes[0] / N;   // 262144

  // Number of K-chunks (= grid = partial count). Prefer 512 (2 blocks/CU);
  // shrink if ws can't hold NS*256*256 fp16 partials.
  int NS = 512;
  while (NS > 1 && (size_t)NS * 65536 * sizeof(_Float16) > ws_size) NS >>= 1;
  const int KC = D / NS;

  zero_kernel<<<1, 64, 0, stream>>>(out);
  gemm_kernel<<<NS, GEMM_THREADS, 0, stream>>>(V1, V2, ws, D, KC);
  loss_kernel<<<N, 256, 0, stream>>>(ws, out, NS, 1.0f / (float)D);
}